// Round 5
// baseline (978.937 us; speedup 1.0000x reference)
//
#include <hip/hip_runtime.h>
#include <math.h>

// SwinTransformerBlock3D: B=2, grid(16,64,64) -> L=65536, C=96, H=6, hd=16,
// win 4^3 -> N=64 tokens/window, shift (2,2,2), 2048 windows, MLP hidden 384.
// All I/O float32.
// R4: 512-thread blocks (2 waves/SIMD) via lane-level split-K + 2-heads-parallel.
//     Same LDS footprint & same per-CU LDS instruction count as the 256-thr version.

// ---------------- Kernel A: LN1 + window attention + proj + residual ----------------
__global__ __launch_bounds__(512, 2)
void swin_attn_kernel(const float* __restrict__ x,
                      const float* __restrict__ n1g, const float* __restrict__ n1b,
                      const float* __restrict__ qkvw, const float* __restrict__ qkvb,
                      const float* __restrict__ projw, const float* __restrict__ projb,
                      const float* __restrict__ btab,
                      float* __restrict__ y)
{
    __shared__ __align__(16) float hT[96 * 66];      // h^T [ch][tok], later o^T
    __shared__ __align__(16) float q_s[6 * 64 * 20]; // q[head][tok][d], pre-scaled
    __shared__ __align__(16) float kT[6 * 16 * 68];  // k^T [head][d][tok]
    __shared__ __align__(16) float v_s[6 * 64 * 20]; // v[head][tok][d]
    __shared__ __align__(16) float wbuf[96 * 96];    // weight tile; aliased as 2x P[64][68]

    const int tid = threadIdx.x;
    const int wid = blockIdx.x;
    const int bb = wid >> 10;
    const int wi = (wid >> 8) & 3;
    const int wx = (wid >> 4) & 15;
    const int wt = wid & 15;

    // ---- phase 1: gather (roll -2) + LayerNorm1 -> hT  (8 lanes/token) ----
    {
        const int n = tid >> 3, p = tid & 7;
        const int a = n >> 4, c = (n >> 2) & 3, e = n & 3;
        const int gi = (wi * 4 + a + 2) & 15;
        const int gx = (wx * 4 + c + 2) & 63;
        const int gt = (wt * 4 + e + 2) & 63;
        const int l = (gi << 12) + (gx << 6) + gt;
        const float* src = x + ((size_t)bb * 65536 + l) * 96 + p * 12;
        float v[12];
        #pragma unroll
        for (int i = 0; i < 3; ++i) {
            const float4 t = *(const float4*)(src + i * 4);
            v[i*4+0] = t.x; v[i*4+1] = t.y; v[i*4+2] = t.z; v[i*4+3] = t.w;
        }
        float s = 0.f, ss = 0.f;
        #pragma unroll
        for (int i = 0; i < 12; ++i) { s += v[i]; ss += v[i] * v[i]; }
        s  += __shfl_xor(s, 1);  s  += __shfl_xor(s, 2);  s  += __shfl_xor(s, 4);
        ss += __shfl_xor(ss, 1); ss += __shfl_xor(ss, 2); ss += __shfl_xor(ss, 4);
        const float mean = s * (1.f / 96.f);
        const float rstd = rsqrtf(ss * (1.f / 96.f) - mean * mean + 1e-5f);
        #pragma unroll
        for (int i = 0; i < 12; ++i) {
            const int ch = p * 12 + i;
            hT[ch * 66 + n] = (v[i] - mean) * rstd * n1g[ch] + n1b[ch];
        }
    }
    __syncthreads();

    // ---- phase 2: QKV = h @ qkv_w + qkv_b (3 tiles of 96 cols), lane split-K ----
    {
        const int pair = tid >> 4;        // 0..31 -> 2 tokens each
        const int jg   = (tid >> 1) & 7;  // 0..7  -> 12 cols each
        const int kg   = tid & 1;         // 0..1  -> 48 k each
        const int n0 = pair * 2;
        const int k0 = kg * 48;
        for (int jt = 0; jt < 3; ++jt) {
            if (jt) __syncthreads();
            #pragma unroll
            for (int i = 0; i < 18; ++i) {
                const int idx = tid + i * 512;
                const int r = idx / 96, cc = idx - r * 96;
                wbuf[idx] = qkvw[r * 288 + jt * 96 + cc];
            }
            __syncthreads();
            float acc[2][12];
            #pragma unroll
            for (int j = 0; j < 12; ++j) { acc[0][j] = 0.f; acc[1][j] = 0.f; }
            #pragma unroll 4
            for (int kk = 0; kk < 48; ++kk) {
                const int k = k0 + kk;
                const float2 h2 = *(const float2*)&hT[k * 66 + n0];
                const float* wr = &wbuf[k * 96 + jg * 12];
                const float4 wa = *(const float4*)(wr + 0);
                const float4 wb = *(const float4*)(wr + 4);
                const float4 wc = *(const float4*)(wr + 8);
                const float w[12] = {wa.x, wa.y, wa.z, wa.w,
                                     wb.x, wb.y, wb.z, wb.w,
                                     wc.x, wc.y, wc.z, wc.w};
                #pragma unroll
                for (int j = 0; j < 12; ++j) {
                    acc[0][j] = fmaf(h2.x, w[j], acc[0][j]);
                    acc[1][j] = fmaf(h2.y, w[j], acc[1][j]);
                }
            }
            #pragma unroll
            for (int j = 0; j < 12; ++j) {   // cross-kg reduce (partner lane)
                acc[0][j] += __shfl_xor(acc[0][j], 1);
                acc[1][j] += __shfl_xor(acc[1][j], 1);
            }
            #pragma unroll
            for (int jj = 0; jj < 6; ++jj) { // each kg lane stores half the cols
                const int j = kg * 6 + jj;
                const int rem = jg * 12 + j;  // 0..95 within tile
                const int hh = rem >> 4, d = rem & 15;
                const float bias = qkvb[jt * 96 + rem];
                const float v0 = acc[0][j] + bias;
                const float v1 = acc[1][j] + bias;
                if (jt == 0) {
                    q_s[(hh * 64 + n0) * 20 + d]       = v0 * 0.25f;  // * hd^-0.5
                    q_s[(hh * 64 + n0 + 1) * 20 + d]   = v1 * 0.25f;
                } else if (jt == 1) {
                    kT[(hh * 16 + d) * 68 + n0]        = v0;
                    kT[(hh * 16 + d) * 68 + n0 + 1]    = v1;
                } else {
                    v_s[(hh * 64 + n0) * 20 + d]       = v0;
                    v_s[(hh * 64 + n0 + 1) * 20 + d]   = v1;
                }
            }
        }
    }
    __syncthreads();

    // ---- phase 3: attention, 2 heads in parallel (3 iterations) ----
    {
        const int h2 = tid >> 8;          // 0/1: which head of the pair
        const int n = (tid >> 2) & 63;
        const int p = tid & 3;
        const int a1 = n >> 4, c1 = (n >> 2) & 3, e1 = n & 3;
        int relidx[16];
        #pragma unroll
        for (int mm = 0; mm < 16; ++mm) {
            const int m = p * 16 + mm;
            const int a2 = m >> 4, c2 = (m >> 2) & 3, e2 = m & 3;
            relidx[mm] = ((a1 - a2 + 3) * 7 + (c1 - c2 + 3)) * 7 + (e1 - e2 + 3);
        }
        float* pbuf = wbuf + h2 * (64 * 68);  // 2 x [64][68] = 8704 <= 9216
        for (int it = 0; it < 3; ++it) {
            const int head = it * 2 + h2;
            float qd[16];
            #pragma unroll
            for (int i = 0; i < 4; ++i)
                *(float4*)&qd[i*4] = *(const float4*)&q_s[(head * 64 + n) * 20 + i * 4];
            float sc[16];
            #pragma unroll
            for (int mm = 0; mm < 16; ++mm) sc[mm] = btab[relidx[mm] * 6 + head];
            #pragma unroll 4
            for (int d = 0; d < 16; ++d) {
                const float* kr = &kT[(head * 16 + d) * 68 + p * 16];
                const float4 k0 = *(const float4*)(kr + 0);
                const float4 k1 = *(const float4*)(kr + 4);
                const float4 k2 = *(const float4*)(kr + 8);
                const float4 k3 = *(const float4*)(kr + 12);
                const float kv[16] = {k0.x,k0.y,k0.z,k0.w, k1.x,k1.y,k1.z,k1.w,
                                      k2.x,k2.y,k2.z,k2.w, k3.x,k3.y,k3.z,k3.w};
                const float qv = qd[d];
                #pragma unroll
                for (int mm = 0; mm < 16; ++mm) sc[mm] = fmaf(qv, kv[mm], sc[mm]);
            }
            float mx = sc[0];
            #pragma unroll
            for (int mm = 1; mm < 16; ++mm) mx = fmaxf(mx, sc[mm]);
            mx = fmaxf(mx, __shfl_xor(mx, 1));
            mx = fmaxf(mx, __shfl_xor(mx, 2));
            float sum = 0.f;
            #pragma unroll
            for (int mm = 0; mm < 16; ++mm) { sc[mm] = __expf(sc[mm] - mx); sum += sc[mm]; }
            sum += __shfl_xor(sum, 1);
            sum += __shfl_xor(sum, 2);
            const float inv = 1.f / sum;
            #pragma unroll
            for (int mm4 = 0; mm4 < 4; ++mm4) {
                const float4 t = make_float4(sc[mm4*4+0]*inv, sc[mm4*4+1]*inv,
                                             sc[mm4*4+2]*inv, sc[mm4*4+3]*inv);
                *(float4*)&pbuf[n * 68 + p * 16 + mm4 * 4] = t;
            }
            __syncthreads();
            // PV: o[n][d], d = p*4..p*4+3
            float4 o4 = make_float4(0.f, 0.f, 0.f, 0.f);
            #pragma unroll 4
            for (int m4 = 0; m4 < 16; ++m4) {
                const float4 pv4 = *(const float4*)&pbuf[n * 68 + m4 * 4];
                const float pv[4] = {pv4.x, pv4.y, pv4.z, pv4.w};
                #pragma unroll
                for (int q = 0; q < 4; ++q) {
                    const float4 v4 = *(const float4*)&v_s[(head * 64 + m4 * 4 + q) * 20 + p * 4];
                    o4.x = fmaf(pv[q], v4.x, o4.x);
                    o4.y = fmaf(pv[q], v4.y, o4.y);
                    o4.z = fmaf(pv[q], v4.z, o4.z);
                    o4.w = fmaf(pv[q], v4.w, o4.w);
                }
            }
            const int cb = head * 16 + p * 4;
            hT[(cb + 0) * 66 + n] = o4.x;   // o^T reuses hT
            hT[(cb + 1) * 66 + n] = o4.y;
            hT[(cb + 2) * 66 + n] = o4.z;
            hT[(cb + 3) * 66 + n] = o4.w;
            __syncthreads();
        }
    }

    // ---- phase 4: proj + residual -> y  (lane split-K) ----
    #pragma unroll
    for (int i = 0; i < 18; ++i) {
        const int idx = tid + i * 512;
        wbuf[idx] = projw[idx];   // [96][96] contiguous
    }
    __syncthreads();
    {
        const int pair = tid >> 4;
        const int jg   = (tid >> 1) & 7;
        const int kg   = tid & 1;
        const int n0 = pair * 2;
        const int k0 = kg * 48;
        float acc[2][12];
        #pragma unroll
        for (int j = 0; j < 12; ++j) { acc[0][j] = 0.f; acc[1][j] = 0.f; }
        #pragma unroll 4
        for (int kk = 0; kk < 48; ++kk) {
            const int k = k0 + kk;
            const float2 o2 = *(const float2*)&hT[k * 66 + n0];
            const float* wr = &wbuf[k * 96 + jg * 12];
            const float4 wa = *(const float4*)(wr + 0);
            const float4 wb = *(const float4*)(wr + 4);
            const float4 wc = *(const float4*)(wr + 8);
            const float w[12] = {wa.x, wa.y, wa.z, wa.w,
                                 wb.x, wb.y, wb.z, wb.w,
                                 wc.x, wc.y, wc.z, wc.w};
            #pragma unroll
            for (int j = 0; j < 12; ++j) {
                acc[0][j] = fmaf(o2.x, w[j], acc[0][j]);
                acc[1][j] = fmaf(o2.y, w[j], acc[1][j]);
            }
        }
        #pragma unroll
        for (int j = 0; j < 12; ++j) {
            acc[0][j] += __shfl_xor(acc[0][j], 1);
            acc[1][j] += __shfl_xor(acc[1][j], 1);
        }
        // each kg lane writes one of the pair's tokens
        {
            const int n = n0 + kg;
            const int a = n >> 4, c = (n >> 2) & 3, e = n & 3;
            const int gi = (wi * 4 + a + 2) & 15;
            const int gx = (wx * 4 + c + 2) & 63;
            const int gt = (wt * 4 + e + 2) & 63;
            const int l = (gi << 12) + (gx << 6) + gt;
            const size_t base = ((size_t)bb * 65536 + l) * 96 + jg * 12;
            #pragma unroll
            for (int jq = 0; jq < 3; ++jq) {
                const float4 xv = *(const float4*)(x + base + jq * 4);
                float4 r;
                r.x = xv.x + acc[kg][jq*4+0] + projb[jg*12 + jq*4+0];
                r.y = xv.y + acc[kg][jq*4+1] + projb[jg*12 + jq*4+1];
                r.z = xv.z + acc[kg][jq*4+2] + projb[jg*12 + jq*4+2];
                r.w = xv.w + acc[kg][jq*4+3] + projb[jg*12 + jq*4+3];
                *(float4*)(y + base + jq * 4) = r;
            }
        }
    }
}

// ---------------- Kernel B: LN2 + MLP (gelu) + residual, in-place on y ----------------
__global__ __launch_bounds__(512, 2)
void swin_mlp_kernel(const float* __restrict__ y,
                     const float* __restrict__ n2g, const float* __restrict__ n2b,
                     const float* __restrict__ w1, const float* __restrict__ b1,
                     const float* __restrict__ w2, const float* __restrict__ b2,
                     float* __restrict__ out)
{
    __shared__ __align__(16) float h2T[96 * 132];  // LN2(y)^T [ch][tok]
    __shared__ __align__(16) float t1T[96 * 132];  // gelu tile^T [k][tok]
    __shared__ __align__(16) float wbuf[96 * 96];

    const int tid = threadIdx.x;
    const size_t tok0 = (size_t)blockIdx.x * 128;

    // ---- phase 1: LayerNorm2 -> h2T  (4 lanes/token) ----
    {
        const int tk = tid >> 2, q4 = tid & 3;
        const float* src = y + (tok0 + tk) * 96 + q4 * 24;
        float v[24];
        #pragma unroll
        for (int i = 0; i < 6; ++i) {
            const float4 t = *(const float4*)(src + i * 4);
            v[i*4+0]=t.x; v[i*4+1]=t.y; v[i*4+2]=t.z; v[i*4+3]=t.w;
        }
        float s = 0.f, ss = 0.f;
        #pragma unroll
        for (int i = 0; i < 24; ++i) { s += v[i]; ss += v[i]*v[i]; }
        s += __shfl_xor(s, 1); s += __shfl_xor(s, 2);
        ss += __shfl_xor(ss, 1); ss += __shfl_xor(ss, 2);
        const float mean = s * (1.f/96.f);
        const float rstd = rsqrtf(ss * (1.f/96.f) - mean*mean + 1e-5f);
        #pragma unroll
        for (int i = 0; i < 24; ++i) {
            const int ch = q4 * 24 + i;
            h2T[ch * 132 + tk] = (v[i]-mean)*rstd*n2g[ch] + n2b[ch];
        }
    }
    __syncthreads();

    const int tq = tid >> 4;         // 0..31 -> 4 tokens each
    const int jg = (tid >> 1) & 7;   // 0..7  -> 12 cols each
    const int kg = tid & 1;          // 0..1  -> 48 k each
    const int n0 = tq * 4;
    const int k0 = kg * 48;
    float acc2[4][12];
    #pragma unroll
    for (int i = 0; i < 4; ++i)
        #pragma unroll
        for (int j = 0; j < 12; ++j) acc2[i][j] = 0.f;

    for (int jt = 0; jt < 4; ++jt) {
        if (jt) __syncthreads();
        // stage W1 tile [96 k][96 j]
        #pragma unroll
        for (int i = 0; i < 18; ++i) {
            const int idx = tid + i * 512;
            const int r = idx / 96, cc = idx - r * 96;
            wbuf[idx] = w1[r * 384 + jt * 96 + cc];
        }
        __syncthreads();
        // layer 1 + gelu -> t1T
        {
            float a1[4][12];
            #pragma unroll
            for (int i = 0; i < 4; ++i)
                #pragma unroll
                for (int j = 0; j < 12; ++j) a1[i][j] = 0.f;
            #pragma unroll 4
            for (int kk = 0; kk < 48; ++kk) {
                const int k = k0 + kk;
                const float4 h4 = *(const float4*)&h2T[k * 132 + n0];
                const float hv[4] = {h4.x, h4.y, h4.z, h4.w};
                const float* wr = &wbuf[k * 96 + jg * 12];
                const float4 wa = *(const float4*)(wr + 0);
                const float4 wb = *(const float4*)(wr + 4);
                const float4 wc = *(const float4*)(wr + 8);
                const float w[12] = {wa.x, wa.y, wa.z, wa.w,
                                     wb.x, wb.y, wb.z, wb.w,
                                     wc.x, wc.y, wc.z, wc.w};
                #pragma unroll
                for (int i = 0; i < 4; ++i)
                    #pragma unroll
                    for (int j = 0; j < 12; ++j)
                        a1[i][j] = fmaf(hv[i], w[j], a1[i][j]);
            }
            #pragma unroll
            for (int i = 0; i < 4; ++i)
                #pragma unroll
                for (int j = 0; j < 12; ++j)
                    a1[i][j] += __shfl_xor(a1[i][j], 1);   // cross-kg reduce
            #pragma unroll
            for (int j = 0; j < 12; ++j) {
                const float bv = b1[jt * 96 + jg * 12 + j];
                #pragma unroll
                for (int ii = 0; ii < 2; ++ii) {           // kg lane stores 2 of 4 tokens
                    const int i = kg * 2 + ii;
                    float t = a1[i][j] + bv;
                    t = 0.5f * t * (1.f + erff(t * 0.70710678118654752f));  // exact gelu
                    t1T[(jg * 12 + j) * 132 + n0 + i] = t;
                }
            }
        }
        __syncthreads();
        // stage W2 tile [96 k][96 c]
        #pragma unroll
        for (int i = 0; i < 18; ++i) {
            const int idx = tid + i * 512;
            const int r = idx / 96, cc = idx - r * 96;
            wbuf[idx] = w2[(jt * 96 + r) * 96 + cc];
        }
        __syncthreads();
        // layer 2 accumulate (split-K partials; reduced once at the end)
        #pragma unroll 4
        for (int kk = 0; kk < 48; ++kk) {
            const int k = k0 + kk;
            const float4 t4 = *(const float4*)&t1T[k * 132 + n0];
            const float tv[4] = {t4.x, t4.y, t4.z, t4.w};
            const float* wr = &wbuf[k * 96 + jg * 12];
            const float4 wa = *(const float4*)(wr + 0);
            const float4 wb = *(const float4*)(wr + 4);
            const float4 wc = *(const float4*)(wr + 8);
            const float w[12] = {wa.x, wa.y, wa.z, wa.w,
                                 wb.x, wb.y, wb.z, wb.w,
                                 wc.x, wc.y, wc.z, wc.w};
            #pragma unroll
            for (int i = 0; i < 4; ++i)
                #pragma unroll
                for (int j = 0; j < 12; ++j)
                    acc2[i][j] = fmaf(tv[i], w[j], acc2[i][j]);
        }
    }

    // ---- epilogue: cross-kg reduce, then out = y + mlp (2 tokens per lane) ----
    #pragma unroll
    for (int i = 0; i < 4; ++i)
        #pragma unroll
        for (int j = 0; j < 12; ++j)
            acc2[i][j] += __shfl_xor(acc2[i][j], 1);
    #pragma unroll
    for (int ii = 0; ii < 2; ++ii) {
        const int i = kg * 2 + ii;
        const size_t base = (tok0 + n0 + i) * 96 + jg * 12;
        #pragma unroll
        for (int jq = 0; jq < 3; ++jq) {
            const float4 yv = *(const float4*)(y + base + jq * 4);
            float4 r;
            r.x = yv.x + acc2[i][jq*4+0] + b2[jg*12 + jq*4+0];
            r.y = yv.y + acc2[i][jq*4+1] + b2[jg*12 + jq*4+1];
            r.z = yv.z + acc2[i][jq*4+2] + b2[jg*12 + jq*4+2];
            r.w = yv.w + acc2[i][jq*4+3] + b2[jg*12 + jq*4+3];
            *(float4*)(out + base + jq * 4) = r;
        }
    }
}

extern "C" void kernel_launch(void* const* d_in, const int* in_sizes, int n_in,
                              void* d_out, int out_size, void* d_ws, size_t ws_size,
                              hipStream_t stream) {
    (void)in_sizes; (void)n_in; (void)d_ws; (void)ws_size; (void)out_size;
    const float* x     = (const float*)d_in[0];
    const float* n1g   = (const float*)d_in[1];
    const float* n1b   = (const float*)d_in[2];
    const float* qkvw  = (const float*)d_in[3];
    const float* qkvb  = (const float*)d_in[4];
    const float* projw = (const float*)d_in[5];
    const float* projb = (const float*)d_in[6];
    const float* btab  = (const float*)d_in[7];
    const float* n2g   = (const float*)d_in[8];
    const float* n2b   = (const float*)d_in[9];
    const float* w1    = (const float*)d_in[10];
    const float* b1    = (const float*)d_in[11];
    const float* w2    = (const float*)d_in[12];
    const float* b2    = (const float*)d_in[13];
    float* out = (float*)d_out;

    swin_attn_kernel<<<2048, 512, 0, stream>>>(x, n1g, n1b, qkvw, qkvb,
                                               projw, projb, btab, out);
    swin_mlp_kernel<<<1024, 512, 0, stream>>>(out, n2g, n2b, w1, b1, w2, b2, out);
}

// Round 6
// 750.896 us; speedup vs baseline: 1.3037x; 1.3037x over previous
//
#include <hip/hip_runtime.h>
#include <math.h>

// SwinTransformerBlock3D: B=2, grid(16,64,64) -> L=65536, C=96, H=6, hd=16,
// win 4^3 -> N=64 tokens/window, shift (2,2,2), 2048 windows, MLP hidden 384.
// All I/O float32.
// R4: 512-thread blocks (2 waves/SIMD) via lane split-K + 2-heads-parallel.
// R6: fix R5's scratch blowup — ALL register-array subscripts compile-time
//     (runtime kg moved into branches; R5 had acc[kg][..] -> 27x WRITE_SIZE).

// ---------------- Kernel A: LN1 + window attention + proj + residual ----------------
__global__ __launch_bounds__(512, 2)
void swin_attn_kernel(const float* __restrict__ x,
                      const float* __restrict__ n1g, const float* __restrict__ n1b,
                      const float* __restrict__ qkvw, const float* __restrict__ qkvb,
                      const float* __restrict__ projw, const float* __restrict__ projb,
                      const float* __restrict__ btab,
                      float* __restrict__ y)
{
    __shared__ __align__(16) float hT[96 * 66];      // h^T [ch][tok], later o^T
    __shared__ __align__(16) float q_s[6 * 64 * 20]; // q[head][tok][d], pre-scaled
    __shared__ __align__(16) float kT[6 * 16 * 68];  // k^T [head][d][tok]
    __shared__ __align__(16) float v_s[6 * 64 * 20]; // v[head][tok][d]
    __shared__ __align__(16) float wbuf[96 * 96];    // weight tile; aliased as 2x P[64][68]

    const int tid = threadIdx.x;
    const int wid = blockIdx.x;
    const int bb = wid >> 10;
    const int wi = (wid >> 8) & 3;
    const int wx = (wid >> 4) & 15;
    const int wt = wid & 15;

    // ---- phase 1: gather (roll -2) + LayerNorm1 -> hT  (8 lanes/token) ----
    {
        const int n = tid >> 3, p = tid & 7;
        const int a = n >> 4, c = (n >> 2) & 3, e = n & 3;
        const int gi = (wi * 4 + a + 2) & 15;
        const int gx = (wx * 4 + c + 2) & 63;
        const int gt = (wt * 4 + e + 2) & 63;
        const int l = (gi << 12) + (gx << 6) + gt;
        const float* src = x + ((size_t)bb * 65536 + l) * 96 + p * 12;
        float v[12];
        #pragma unroll
        for (int i = 0; i < 3; ++i) {
            const float4 t = *(const float4*)(src + i * 4);
            v[i*4+0] = t.x; v[i*4+1] = t.y; v[i*4+2] = t.z; v[i*4+3] = t.w;
        }
        float s = 0.f, ss = 0.f;
        #pragma unroll
        for (int i = 0; i < 12; ++i) { s += v[i]; ss += v[i] * v[i]; }
        s  += __shfl_xor(s, 1);  s  += __shfl_xor(s, 2);  s  += __shfl_xor(s, 4);
        ss += __shfl_xor(ss, 1); ss += __shfl_xor(ss, 2); ss += __shfl_xor(ss, 4);
        const float mean = s * (1.f / 96.f);
        const float rstd = rsqrtf(ss * (1.f / 96.f) - mean * mean + 1e-5f);
        #pragma unroll
        for (int i = 0; i < 12; ++i) {
            const int ch = p * 12 + i;
            hT[ch * 66 + n] = (v[i] - mean) * rstd * n1g[ch] + n1b[ch];
        }
    }
    __syncthreads();

    // ---- phase 2: QKV = h @ qkv_w + qkv_b (3 tiles of 96 cols), lane split-K ----
    {
        const int pair = tid >> 4;        // 0..31 -> 2 tokens each
        const int jg   = (tid >> 1) & 7;  // 0..7  -> 12 cols each
        const int kg   = tid & 1;         // 0..1  -> 48 k each
        const int n0 = pair * 2;
        const int k0 = kg * 48;
        for (int jt = 0; jt < 3; ++jt) {
            if (jt) __syncthreads();
            #pragma unroll
            for (int i = 0; i < 18; ++i) {
                const int idx = tid + i * 512;
                const int r = idx / 96, cc = idx - r * 96;
                wbuf[idx] = qkvw[r * 288 + jt * 96 + cc];
            }
            __syncthreads();
            float acc[2][12];
            #pragma unroll
            for (int j = 0; j < 12; ++j) { acc[0][j] = 0.f; acc[1][j] = 0.f; }
            #pragma unroll 4
            for (int kk = 0; kk < 48; ++kk) {
                const int k = k0 + kk;
                const float2 h2 = *(const float2*)&hT[k * 66 + n0];
                const float* wr = &wbuf[k * 96 + jg * 12];
                const float4 wa = *(const float4*)(wr + 0);
                const float4 wb = *(const float4*)(wr + 4);
                const float4 wc = *(const float4*)(wr + 8);
                const float w[12] = {wa.x, wa.y, wa.z, wa.w,
                                     wb.x, wb.y, wb.z, wb.w,
                                     wc.x, wc.y, wc.z, wc.w};
                #pragma unroll
                for (int j = 0; j < 12; ++j) {
                    acc[0][j] = fmaf(h2.x, w[j], acc[0][j]);
                    acc[1][j] = fmaf(h2.y, w[j], acc[1][j]);
                }
            }
            #pragma unroll
            for (int j = 0; j < 12; ++j) {   // cross-kg reduce (partner lane)
                acc[0][j] += __shfl_xor(acc[0][j], 1);
                acc[1][j] += __shfl_xor(acc[1][j], 1);
            }
            // each kg lane stores half the cols — STATIC register indices only
            // (R5 lesson: acc[kg*6+jj] forced acc to scratch -> 27x WRITE_SIZE)
#define QKV_STORE(J) { \
                const int rem = jg * 12 + (J); \
                const int hh = rem >> 4, d = rem & 15; \
                const float bias = qkvb[jt * 96 + rem]; \
                const float v0 = acc[0][(J)] + bias; \
                const float v1 = acc[1][(J)] + bias; \
                if (jt == 0) { \
                    q_s[(hh * 64 + n0) * 20 + d]       = v0 * 0.25f; \
                    q_s[(hh * 64 + n0 + 1) * 20 + d]   = v1 * 0.25f; \
                } else if (jt == 1) { \
                    kT[(hh * 16 + d) * 68 + n0]        = v0; \
                    kT[(hh * 16 + d) * 68 + n0 + 1]    = v1; \
                } else { \
                    v_s[(hh * 64 + n0) * 20 + d]       = v0; \
                    v_s[(hh * 64 + n0 + 1) * 20 + d]   = v1; \
                } }
            if (kg == 0) {
                QKV_STORE(0) QKV_STORE(1) QKV_STORE(2)
                QKV_STORE(3) QKV_STORE(4) QKV_STORE(5)
            } else {
                QKV_STORE(6) QKV_STORE(7) QKV_STORE(8)
                QKV_STORE(9) QKV_STORE(10) QKV_STORE(11)
            }
#undef QKV_STORE
        }
    }
    __syncthreads();

    // ---- phase 3: attention, 2 heads in parallel (3 iterations) ----
    {
        const int h2 = tid >> 8;          // 0/1: which head of the pair
        const int n = (tid >> 2) & 63;
        const int p = tid & 3;
        const int a1 = n >> 4, c1 = (n >> 2) & 3, e1 = n & 3;
        int relidx[16];
        #pragma unroll
        for (int mm = 0; mm < 16; ++mm) {
            const int m = p * 16 + mm;
            const int a2 = m >> 4, c2 = (m >> 2) & 3, e2 = m & 3;
            relidx[mm] = ((a1 - a2 + 3) * 7 + (c1 - c2 + 3)) * 7 + (e1 - e2 + 3);
        }
        float* pbuf = wbuf + h2 * (64 * 68);  // 2 x [64][68] = 8704 <= 9216
        for (int it = 0; it < 3; ++it) {
            const int head = it * 2 + h2;
            float qd[16];
            #pragma unroll
            for (int i = 0; i < 4; ++i)
                *(float4*)&qd[i*4] = *(const float4*)&q_s[(head * 64 + n) * 20 + i * 4];
            float sc[16];
            #pragma unroll
            for (int mm = 0; mm < 16; ++mm) sc[mm] = btab[relidx[mm] * 6 + head];
            #pragma unroll 4
            for (int d = 0; d < 16; ++d) {
                const float* kr = &kT[(head * 16 + d) * 68 + p * 16];
                const float4 k0 = *(const float4*)(kr + 0);
                const float4 k1 = *(const float4*)(kr + 4);
                const float4 k2 = *(const float4*)(kr + 8);
                const float4 k3 = *(const float4*)(kr + 12);
                const float kv[16] = {k0.x,k0.y,k0.z,k0.w, k1.x,k1.y,k1.z,k1.w,
                                      k2.x,k2.y,k2.z,k2.w, k3.x,k3.y,k3.z,k3.w};
                const float qv = qd[d];
                #pragma unroll
                for (int mm = 0; mm < 16; ++mm) sc[mm] = fmaf(qv, kv[mm], sc[mm]);
            }
            float mx = sc[0];
            #pragma unroll
            for (int mm = 1; mm < 16; ++mm) mx = fmaxf(mx, sc[mm]);
            mx = fmaxf(mx, __shfl_xor(mx, 1));
            mx = fmaxf(mx, __shfl_xor(mx, 2));
            float sum = 0.f;
            #pragma unroll
            for (int mm = 0; mm < 16; ++mm) { sc[mm] = __expf(sc[mm] - mx); sum += sc[mm]; }
            sum += __shfl_xor(sum, 1);
            sum += __shfl_xor(sum, 2);
            const float inv = 1.f / sum;
            #pragma unroll
            for (int mm4 = 0; mm4 < 4; ++mm4) {
                const float4 t = make_float4(sc[mm4*4+0]*inv, sc[mm4*4+1]*inv,
                                             sc[mm4*4+2]*inv, sc[mm4*4+3]*inv);
                *(float4*)&pbuf[n * 68 + p * 16 + mm4 * 4] = t;
            }
            __syncthreads();
            // PV: o[n][d], d = p*4..p*4+3
            float4 o4 = make_float4(0.f, 0.f, 0.f, 0.f);
            #pragma unroll 4
            for (int m4 = 0; m4 < 16; ++m4) {
                const float4 pv4 = *(const float4*)&pbuf[n * 68 + m4 * 4];
                const float pv[4] = {pv4.x, pv4.y, pv4.z, pv4.w};
                #pragma unroll
                for (int q = 0; q < 4; ++q) {
                    const float4 v4 = *(const float4*)&v_s[(head * 64 + m4 * 4 + q) * 20 + p * 4];
                    o4.x = fmaf(pv[q], v4.x, o4.x);
                    o4.y = fmaf(pv[q], v4.y, o4.y);
                    o4.z = fmaf(pv[q], v4.z, o4.z);
                    o4.w = fmaf(pv[q], v4.w, o4.w);
                }
            }
            const int cb = head * 16 + p * 4;
            hT[(cb + 0) * 66 + n] = o4.x;   // o^T reuses hT
            hT[(cb + 1) * 66 + n] = o4.y;
            hT[(cb + 2) * 66 + n] = o4.z;
            hT[(cb + 3) * 66 + n] = o4.w;
            __syncthreads();
        }
    }

    // ---- phase 4: proj + residual -> y  (lane split-K) ----
    #pragma unroll
    for (int i = 0; i < 18; ++i) {
        const int idx = tid + i * 512;
        wbuf[idx] = projw[idx];   // [96][96] contiguous
    }
    __syncthreads();
    {
        const int pair = tid >> 4;
        const int jg   = (tid >> 1) & 7;
        const int kg   = tid & 1;
        const int n0 = pair * 2;
        const int k0 = kg * 48;
        float acc[2][12];
        #pragma unroll
        for (int j = 0; j < 12; ++j) { acc[0][j] = 0.f; acc[1][j] = 0.f; }
        #pragma unroll 4
        for (int kk = 0; kk < 48; ++kk) {
            const int k = k0 + kk;
            const float2 o2 = *(const float2*)&hT[k * 66 + n0];
            const float* wr = &wbuf[k * 96 + jg * 12];
            const float4 wa = *(const float4*)(wr + 0);
            const float4 wb = *(const float4*)(wr + 4);
            const float4 wc = *(const float4*)(wr + 8);
            const float w[12] = {wa.x, wa.y, wa.z, wa.w,
                                 wb.x, wb.y, wb.z, wb.w,
                                 wc.x, wc.y, wc.z, wc.w};
            #pragma unroll
            for (int j = 0; j < 12; ++j) {
                acc[0][j] = fmaf(o2.x, w[j], acc[0][j]);
                acc[1][j] = fmaf(o2.y, w[j], acc[1][j]);
            }
        }
        #pragma unroll
        for (int j = 0; j < 12; ++j) {
            acc[0][j] += __shfl_xor(acc[0][j], 1);
            acc[1][j] += __shfl_xor(acc[1][j], 1);
        }
        // each kg lane writes one token of the pair — STATIC acc row per branch
        {
            const int n = n0 + kg;
            const int a = n >> 4, c = (n >> 2) & 3, e = n & 3;
            const int gi = (wi * 4 + a + 2) & 15;
            const int gx = (wx * 4 + c + 2) & 63;
            const int gt = (wt * 4 + e + 2) & 63;
            const int l = (gi << 12) + (gx << 6) + gt;
            const size_t base = ((size_t)bb * 65536 + l) * 96 + jg * 12;
            if (kg == 0) {
                #pragma unroll
                for (int jq = 0; jq < 3; ++jq) {
                    const float4 xv = *(const float4*)(x + base + jq * 4);
                    float4 r;
                    r.x = xv.x + acc[0][jq*4+0] + projb[jg*12 + jq*4+0];
                    r.y = xv.y + acc[0][jq*4+1] + projb[jg*12 + jq*4+1];
                    r.z = xv.z + acc[0][jq*4+2] + projb[jg*12 + jq*4+2];
                    r.w = xv.w + acc[0][jq*4+3] + projb[jg*12 + jq*4+3];
                    *(float4*)(y + base + jq * 4) = r;
                }
            } else {
                #pragma unroll
                for (int jq = 0; jq < 3; ++jq) {
                    const float4 xv = *(const float4*)(x + base + jq * 4);
                    float4 r;
                    r.x = xv.x + acc[1][jq*4+0] + projb[jg*12 + jq*4+0];
                    r.y = xv.y + acc[1][jq*4+1] + projb[jg*12 + jq*4+1];
                    r.z = xv.z + acc[1][jq*4+2] + projb[jg*12 + jq*4+2];
                    r.w = xv.w + acc[1][jq*4+3] + projb[jg*12 + jq*4+3];
                    *(float4*)(y + base + jq * 4) = r;
                }
            }
        }
    }
}

// ---------------- Kernel B: LN2 + MLP (gelu) + residual, in-place on y ----------------
__global__ __launch_bounds__(512, 2)
void swin_mlp_kernel(const float* __restrict__ y,
                     const float* __restrict__ n2g, const float* __restrict__ n2b,
                     const float* __restrict__ w1, const float* __restrict__ b1,
                     const float* __restrict__ w2, const float* __restrict__ b2,
                     float* __restrict__ out)
{
    __shared__ __align__(16) float h2T[96 * 132];  // LN2(y)^T [ch][tok]
    __shared__ __align__(16) float t1T[96 * 132];  // gelu tile^T [k][tok]
    __shared__ __align__(16) float wbuf[96 * 96];

    const int tid = threadIdx.x;
    const size_t tok0 = (size_t)blockIdx.x * 128;

    // ---- phase 1: LayerNorm2 -> h2T  (4 lanes/token) ----
    {
        const int tk = tid >> 2, q4 = tid & 3;
        const float* src = y + (tok0 + tk) * 96 + q4 * 24;
        float v[24];
        #pragma unroll
        for (int i = 0; i < 6; ++i) {
            const float4 t = *(const float4*)(src + i * 4);
            v[i*4+0]=t.x; v[i*4+1]=t.y; v[i*4+2]=t.z; v[i*4+3]=t.w;
        }
        float s = 0.f, ss = 0.f;
        #pragma unroll
        for (int i = 0; i < 24; ++i) { s += v[i]; ss += v[i]*v[i]; }
        s += __shfl_xor(s, 1); s += __shfl_xor(s, 2);
        ss += __shfl_xor(ss, 1); ss += __shfl_xor(ss, 2);
        const float mean = s * (1.f/96.f);
        const float rstd = rsqrtf(ss * (1.f/96.f) - mean*mean + 1e-5f);
        #pragma unroll
        for (int i = 0; i < 24; ++i) {
            const int ch = q4 * 24 + i;
            h2T[ch * 132 + tk] = (v[i]-mean)*rstd*n2g[ch] + n2b[ch];
        }
    }
    __syncthreads();

    const int tq = tid >> 4;         // 0..31 -> 4 tokens each
    const int jg = (tid >> 1) & 7;   // 0..7  -> 12 cols each
    const int kg = tid & 1;          // 0..1  -> 48 k each
    const int n0 = tq * 4;
    const int k0 = kg * 48;
    float acc2[4][12];
    #pragma unroll
    for (int i = 0; i < 4; ++i)
        #pragma unroll
        for (int j = 0; j < 12; ++j) acc2[i][j] = 0.f;

    for (int jt = 0; jt < 4; ++jt) {
        if (jt) __syncthreads();
        // stage W1 tile [96 k][96 j]
        #pragma unroll
        for (int i = 0; i < 18; ++i) {
            const int idx = tid + i * 512;
            const int r = idx / 96, cc = idx - r * 96;
            wbuf[idx] = w1[r * 384 + jt * 96 + cc];
        }
        __syncthreads();
        // layer 1 + gelu -> t1T
        {
            float a1[4][12];
            #pragma unroll
            for (int i = 0; i < 4; ++i)
                #pragma unroll
                for (int j = 0; j < 12; ++j) a1[i][j] = 0.f;
            #pragma unroll 4
            for (int kk = 0; kk < 48; ++kk) {
                const int k = k0 + kk;
                const float4 h4 = *(const float4*)&h2T[k * 132 + n0];
                const float hv[4] = {h4.x, h4.y, h4.z, h4.w};
                const float* wr = &wbuf[k * 96 + jg * 12];
                const float4 wa = *(const float4*)(wr + 0);
                const float4 wb = *(const float4*)(wr + 4);
                const float4 wc = *(const float4*)(wr + 8);
                const float w[12] = {wa.x, wa.y, wa.z, wa.w,
                                     wb.x, wb.y, wb.z, wb.w,
                                     wc.x, wc.y, wc.z, wc.w};
                #pragma unroll
                for (int i = 0; i < 4; ++i)
                    #pragma unroll
                    for (int j = 0; j < 12; ++j)
                        a1[i][j] = fmaf(hv[i], w[j], a1[i][j]);
            }
            #pragma unroll
            for (int i = 0; i < 4; ++i)
                #pragma unroll
                for (int j = 0; j < 12; ++j)
                    a1[i][j] += __shfl_xor(a1[i][j], 1);   // cross-kg reduce
            // kg lane stores 2 of 4 tokens — STATIC a1 rows per branch
            #pragma unroll
            for (int j = 0; j < 12; ++j) {
                const float bv = b1[jt * 96 + jg * 12 + j];
                float t0, t1;
                if (kg == 0) { t0 = a1[0][j] + bv; t1 = a1[1][j] + bv; }
                else         { t0 = a1[2][j] + bv; t1 = a1[3][j] + bv; }
                t0 = 0.5f * t0 * (1.f + erff(t0 * 0.70710678118654752f));
                t1 = 0.5f * t1 * (1.f + erff(t1 * 0.70710678118654752f));
                const int ib = n0 + kg * 2;          // LDS addr may be runtime
                t1T[(jg * 12 + j) * 132 + ib + 0] = t0;
                t1T[(jg * 12 + j) * 132 + ib + 1] = t1;
            }
        }
        __syncthreads();
        // stage W2 tile [96 k][96 c]
        #pragma unroll
        for (int i = 0; i < 18; ++i) {
            const int idx = tid + i * 512;
            const int r = idx / 96, cc = idx - r * 96;
            wbuf[idx] = w2[(jt * 96 + r) * 96 + cc];
        }
        __syncthreads();
        // layer 2 accumulate (split-K partials; reduced once at the end)
        #pragma unroll 4
        for (int kk = 0; kk < 48; ++kk) {
            const int k = k0 + kk;
            const float4 t4 = *(const float4*)&t1T[k * 132 + n0];
            const float tv[4] = {t4.x, t4.y, t4.z, t4.w};
            const float* wr = &wbuf[k * 96 + jg * 12];
            const float4 wa = *(const float4*)(wr + 0);
            const float4 wb = *(const float4*)(wr + 4);
            const float4 wc = *(const float4*)(wr + 8);
            const float w[12] = {wa.x, wa.y, wa.z, wa.w,
                                 wb.x, wb.y, wb.z, wb.w,
                                 wc.x, wc.y, wc.z, wc.w};
            #pragma unroll
            for (int i = 0; i < 4; ++i)
                #pragma unroll
                for (int j = 0; j < 12; ++j)
                    acc2[i][j] = fmaf(tv[i], w[j], acc2[i][j]);
        }
    }

    // ---- epilogue: cross-kg reduce, then out = y + mlp (2 tokens/lane) ----
    #pragma unroll
    for (int i = 0; i < 4; ++i)
        #pragma unroll
        for (int j = 0; j < 12; ++j)
            acc2[i][j] += __shfl_xor(acc2[i][j], 1);
    // STATIC acc2 rows per branch (R5 lesson)
#define MLP_OUT(I) { \
    const size_t base = (tok0 + n0 + (I)) * 96 + jg * 12; \
    _Pragma("unroll") \
    for (int jq = 0; jq < 3; ++jq) { \
        const float4 yv = *(const float4*)(y + base + jq * 4); \
        float4 r; \
        r.x = yv.x + acc2[(I)][jq*4+0] + b2[jg*12 + jq*4+0]; \
        r.y = yv.y + acc2[(I)][jq*4+1] + b2[jg*12 + jq*4+1]; \
        r.z = yv.z + acc2[(I)][jq*4+2] + b2[jg*12 + jq*4+2]; \
        r.w = yv.w + acc2[(I)][jq*4+3] + b2[jg*12 + jq*4+3]; \
        *(float4*)(out + base + jq * 4) = r; \
    } }
    if (kg == 0) { MLP_OUT(0) MLP_OUT(1) }
    else         { MLP_OUT(2) MLP_OUT(3) }
#undef MLP_OUT
}

extern "C" void kernel_launch(void* const* d_in, const int* in_sizes, int n_in,
                              void* d_out, int out_size, void* d_ws, size_t ws_size,
                              hipStream_t stream) {
    (void)in_sizes; (void)n_in; (void)d_ws; (void)ws_size; (void)out_size;
    const float* x     = (const float*)d_in[0];
    const float* n1g   = (const float*)d_in[1];
    const float* n1b   = (const float*)d_in[2];
    const float* qkvw  = (const float*)d_in[3];
    const float* qkvb  = (const float*)d_in[4];
    const float* projw = (const float*)d_in[5];
    const float* projb = (const float*)d_in[6];
    const float* btab  = (const float*)d_in[7];
    const float* n2g   = (const float*)d_in[8];
    const float* n2b   = (const float*)d_in[9];
    const float* w1    = (const float*)d_in[10];
    const float* b1    = (const float*)d_in[11];
    const float* w2    = (const float*)d_in[12];
    const float* b2    = (const float*)d_in[13];
    float* out = (float*)d_out;

    swin_attn_kernel<<<2048, 512, 0, stream>>>(x, n1g, n1b, qkvw, qkvb,
                                               projw, projb, btab, out);
    swin_mlp_kernel<<<1024, 512, 0, stream>>>(out, n2g, n2b, w1, b1, w2, b2, out);
}

// Round 7
// 413.727 us; speedup vs baseline: 2.3661x; 1.8150x over previous
//
#include <hip/hip_runtime.h>
#include <math.h>

// SwinTransformerBlock3D: B=2, grid(16,64,64) -> L=65536, C=96, H=6, hd=16,
// win 4^3 -> N=64 tokens/window, shift (2,2,2), 2048 windows, MLP hidden 384.
// All I/O float32.
// R7: weight GEMMs (QKV, proj, MLP1, MLP2) -> bf16 MFMA 16x16x32, fp32 accum.
//     R6 was LDS-pipe-bound (per-CU LDS cycles >> per-SIMD VALU cycles).
//     Both mfma operands loaded [outdim][k-contig] with identical formula ->
//     k-slot permutation cancels; C layout: col=lane&15, row=(lane>>4)*4+reg.
//     LN / softmax / attention QK,PV stay f32 (unchanged from R6).

typedef __attribute__((ext_vector_type(8))) short short8;
typedef __attribute__((ext_vector_type(4))) float floatx4;

__device__ __forceinline__ ushort f2bf(float f) {
    union { float f; uint u; } v; v.f = f;
    uint r = v.u + 0x7FFFu + ((v.u >> 16) & 1u);   // RNE
    return (ushort)(r >> 16);
}
__device__ __forceinline__ uint pk2(float a, float b) {
    return (uint)f2bf(a) | ((uint)f2bf(b) << 16);
}

// ---------------- Kernel A: LN1 + window attention + proj + residual ----------------
__global__ __launch_bounds__(512, 2)
void swin_attn_kernel(const float* __restrict__ x,
                      const float* __restrict__ n1g, const float* __restrict__ n1b,
                      const float* __restrict__ qkvw, const float* __restrict__ qkvb,
                      const float* __restrict__ projw, const float* __restrict__ projb,
                      const float* __restrict__ btab,
                      float* __restrict__ y)
{
    // upool unions: phases 1/2/4 use hA(13312B)+wT(19968B); phase 3 uses pbuf(34816B)
    __shared__ __align__(16) float upool[2 * 64 * 68];
    __shared__ __align__(16) float q_s[6 * 64 * 20]; // q[head][tok][d] f32, pre-scaled
    __shared__ __align__(16) float kT6[6 * 16 * 68]; // k^T [head][d][tok] f32
    __shared__ __align__(16) float v_s[6 * 64 * 20]; // v[head][tok][d] f32
    __shared__ __align__(16) ushort oA[64 * 104];    // attn out bf16 [tok][ch]
    ushort* hA = (ushort*)upool;                     // [64][104] bf16 LN1 out
    ushort* wT = ((ushort*)upool) + 64 * 104;        // [96][104] bf16 W^T tile

    const int tid = threadIdx.x;
    const int wid = blockIdx.x;
    const int bb = wid >> 10;
    const int wi = (wid >> 8) & 3;
    const int wx = (wid >> 4) & 15;
    const int wt = wid & 15;

    // ---- phase 1: gather (roll -2) + LayerNorm1 -> hA bf16 [tok][104] ----
    {
        const int n = tid >> 3, p = tid & 7;
        const int a = n >> 4, c = (n >> 2) & 3, e = n & 3;
        const int gi = (wi * 4 + a + 2) & 15;
        const int gx = (wx * 4 + c + 2) & 63;
        const int gt = (wt * 4 + e + 2) & 63;
        const int l = (gi << 12) + (gx << 6) + gt;
        const float* src = x + ((size_t)bb * 65536 + l) * 96 + p * 12;
        float v[12];
        #pragma unroll
        for (int i = 0; i < 3; ++i) {
            const float4 t = *(const float4*)(src + i * 4);
            v[i*4+0] = t.x; v[i*4+1] = t.y; v[i*4+2] = t.z; v[i*4+3] = t.w;
        }
        float s = 0.f, ss = 0.f;
        #pragma unroll
        for (int i = 0; i < 12; ++i) { s += v[i]; ss += v[i] * v[i]; }
        s  += __shfl_xor(s, 1);  s  += __shfl_xor(s, 2);  s  += __shfl_xor(s, 4);
        ss += __shfl_xor(ss, 1); ss += __shfl_xor(ss, 2); ss += __shfl_xor(ss, 4);
        const float mean = s * (1.f / 96.f);
        const float rstd = rsqrtf(ss * (1.f / 96.f) - mean * mean + 1e-5f);
        float nv[12];
        #pragma unroll
        for (int i = 0; i < 12; ++i) {
            const int ch = p * 12 + i;
            nv[i] = (v[i] - mean) * rstd * n1g[ch] + n1b[ch];
        }
        #pragma unroll
        for (int j = 0; j < 6; ++j)
            *(uint*)&hA[n * 104 + p * 12 + 2 * j] = pk2(nv[2*j], nv[2*j+1]);
    }
    __syncthreads();

    const int wv = tid >> 6, lane = tid & 63;
    const int lr = lane & 15, lg = lane >> 4;
    const int tr = wv >> 1;        // token tile (0..3)
    const int chf = wv & 1;        // col half (48 cols)

    // A fragments: tokens tr*16+lr, k-chunks 0..2 (reused across jt)
    const short8 afr0 = *(const short8*)&hA[(tr*16 + lr) * 104 +  0 + lg * 8];
    const short8 afr1 = *(const short8*)&hA[(tr*16 + lr) * 104 + 32 + lg * 8];
    const short8 afr2 = *(const short8*)&hA[(tr*16 + lr) * 104 + 64 + lg * 8];

    // ---- phase 2: QKV via MFMA (3 jt tiles of 96 cols) ----
    for (int jt = 0; jt < 3; ++jt) {
        if (jt) __syncthreads();
        // stage qkv_w[:, jt*96..+96]^T -> wT[col][k] bf16 (k-pairs packed)
        #pragma unroll
        for (int it = 0; it < 3; ++it) {
            const int idx = tid + it * 512;
            if (idx < 1152) {
                const int rp = idx / 24, c4 = idx - rp * 24;
                const float* s0 = qkvw + (2 * rp) * 288 + jt * 96 + c4 * 4;
                const float4 r0 = *(const float4*)s0;
                const float4 r1 = *(const float4*)(s0 + 288);
                const int base = (c4 * 4) * 104 + 2 * rp;
                *(uint*)&wT[base      ] = pk2(r0.x, r1.x);
                *(uint*)&wT[base + 104] = pk2(r0.y, r1.y);
                *(uint*)&wT[base + 208] = pk2(r0.z, r1.z);
                *(uint*)&wT[base + 312] = pk2(r0.w, r1.w);
            }
        }
        __syncthreads();
        floatx4 acc0 = {0.f,0.f,0.f,0.f}, acc1 = {0.f,0.f,0.f,0.f}, acc2 = {0.f,0.f,0.f,0.f};
#define QKV_TILE(CT, ACC) { \
        const ushort* bp = &wT[(chf*48 + (CT)*16 + lr) * 104 + lg * 8]; \
        const short8 b0 = *(const short8*)(bp); \
        const short8 b1 = *(const short8*)(bp + 32); \
        const short8 b2 = *(const short8*)(bp + 64); \
        ACC = __builtin_amdgcn_mfma_f32_16x16x32_bf16(afr0, b0, ACC, 0, 0, 0); \
        ACC = __builtin_amdgcn_mfma_f32_16x16x32_bf16(afr1, b1, ACC, 0, 0, 0); \
        ACC = __builtin_amdgcn_mfma_f32_16x16x32_bf16(afr2, b2, ACC, 0, 0, 0); }
        QKV_TILE(0, acc0) QKV_TILE(1, acc1) QKV_TILE(2, acc2)
#undef QKV_TILE
#define QKV_ST(CT, ACC) { \
        const int col = chf*48 + (CT)*16 + lr; \
        const int hh = col >> 4, d = col & 15; \
        const float bias = qkvb[jt * 96 + col]; \
        _Pragma("unroll") \
        for (int r = 0; r < 4; ++r) { \
            const int tok = tr*16 + lg*4 + r; \
            const float val = ACC[r] + bias; \
            if (jt == 0)      q_s[(hh*64 + tok)*20 + d] = val * 0.25f; \
            else if (jt == 1) kT6[(hh*16 + d)*68 + tok] = val; \
            else              v_s[(hh*64 + tok)*20 + d] = val; \
        } }
        QKV_ST(0, acc0) QKV_ST(1, acc1) QKV_ST(2, acc2)
#undef QKV_ST
    }
    __syncthreads();

    // ---- phase 3: attention (f32, unchanged math), 2 heads in parallel ----
    {
        const int h2i = tid >> 8;         // 0/1
        const int n = (tid >> 2) & 63;
        const int p = tid & 3;
        const int a1i = n >> 4, c1 = (n >> 2) & 3, e1 = n & 3;
        int relidx[16];
        #pragma unroll
        for (int mm = 0; mm < 16; ++mm) {
            const int m = p * 16 + mm;
            const int a2 = m >> 4, c2 = (m >> 2) & 3, e2 = m & 3;
            relidx[mm] = ((a1i - a2 + 3) * 7 + (c1 - c2 + 3)) * 7 + (e1 - e2 + 3);
        }
        float* pbuf = upool + h2i * (64 * 68);   // 2 x [64][68]
        for (int it = 0; it < 3; ++it) {
            const int head = it * 2 + h2i;
            float qd[16];
            #pragma unroll
            for (int i = 0; i < 4; ++i)
                *(float4*)&qd[i*4] = *(const float4*)&q_s[(head * 64 + n) * 20 + i * 4];
            float sc[16];
            #pragma unroll
            for (int mm = 0; mm < 16; ++mm) sc[mm] = btab[relidx[mm] * 6 + head];
            #pragma unroll 4
            for (int d = 0; d < 16; ++d) {
                const float* kr = &kT6[(head * 16 + d) * 68 + p * 16];
                const float4 k0 = *(const float4*)(kr + 0);
                const float4 k1 = *(const float4*)(kr + 4);
                const float4 k2 = *(const float4*)(kr + 8);
                const float4 k3 = *(const float4*)(kr + 12);
                const float kv[16] = {k0.x,k0.y,k0.z,k0.w, k1.x,k1.y,k1.z,k1.w,
                                      k2.x,k2.y,k2.z,k2.w, k3.x,k3.y,k3.z,k3.w};
                const float qv = qd[d];
                #pragma unroll
                for (int mm = 0; mm < 16; ++mm) sc[mm] = fmaf(qv, kv[mm], sc[mm]);
            }
            float mx = sc[0];
            #pragma unroll
            for (int mm = 1; mm < 16; ++mm) mx = fmaxf(mx, sc[mm]);
            mx = fmaxf(mx, __shfl_xor(mx, 1));
            mx = fmaxf(mx, __shfl_xor(mx, 2));
            float sum = 0.f;
            #pragma unroll
            for (int mm = 0; mm < 16; ++mm) { sc[mm] = __expf(sc[mm] - mx); sum += sc[mm]; }
            sum += __shfl_xor(sum, 1);
            sum += __shfl_xor(sum, 2);
            const float inv = 1.f / sum;
            #pragma unroll
            for (int mm4 = 0; mm4 < 4; ++mm4) {
                const float4 t = make_float4(sc[mm4*4+0]*inv, sc[mm4*4+1]*inv,
                                             sc[mm4*4+2]*inv, sc[mm4*4+3]*inv);
                *(float4*)&pbuf[n * 68 + p * 16 + mm4 * 4] = t;
            }
            __syncthreads();
            float4 o4 = make_float4(0.f, 0.f, 0.f, 0.f);
            #pragma unroll 4
            for (int m4 = 0; m4 < 16; ++m4) {
                const float4 pv4 = *(const float4*)&pbuf[n * 68 + m4 * 4];
                const float pv[4] = {pv4.x, pv4.y, pv4.z, pv4.w};
                #pragma unroll
                for (int q = 0; q < 4; ++q) {
                    const float4 v4 = *(const float4*)&v_s[(head * 64 + m4 * 4 + q) * 20 + p * 4];
                    o4.x = fmaf(pv[q], v4.x, o4.x);
                    o4.y = fmaf(pv[q], v4.y, o4.y);
                    o4.z = fmaf(pv[q], v4.z, o4.z);
                    o4.w = fmaf(pv[q], v4.w, o4.w);
                }
            }
            const int cb = head * 16 + p * 4;
            *(uint*)&oA[n * 104 + cb]     = pk2(o4.x, o4.y);
            *(uint*)&oA[n * 104 + cb + 2] = pk2(o4.z, o4.w);
            __syncthreads();
        }
    }

    // ---- phase 4: proj via MFMA + residual -> y ----
    #pragma unroll
    for (int it = 0; it < 3; ++it) {
        const int idx = tid + it * 512;
        if (idx < 1152) {
            const int rp = idx / 24, c4 = idx - rp * 24;
            const float* s0 = projw + (2 * rp) * 96 + c4 * 4;
            const float4 r0 = *(const float4*)s0;
            const float4 r1 = *(const float4*)(s0 + 96);
            const int base = (c4 * 4) * 104 + 2 * rp;
            *(uint*)&wT[base      ] = pk2(r0.x, r1.x);
            *(uint*)&wT[base + 104] = pk2(r0.y, r1.y);
            *(uint*)&wT[base + 208] = pk2(r0.z, r1.z);
            *(uint*)&wT[base + 312] = pk2(r0.w, r1.w);
        }
    }
    __syncthreads();
    {
        const short8 ofr0 = *(const short8*)&oA[(tr*16 + lr) * 104 +  0 + lg * 8];
        const short8 ofr1 = *(const short8*)&oA[(tr*16 + lr) * 104 + 32 + lg * 8];
        const short8 ofr2 = *(const short8*)&oA[(tr*16 + lr) * 104 + 64 + lg * 8];
        floatx4 pa0 = {0.f,0.f,0.f,0.f}, pa1 = {0.f,0.f,0.f,0.f}, pa2 = {0.f,0.f,0.f,0.f};
#define PRJ_TILE(CT, ACC) { \
        const ushort* bp = &wT[(chf*48 + (CT)*16 + lr) * 104 + lg * 8]; \
        const short8 b0 = *(const short8*)(bp); \
        const short8 b1 = *(const short8*)(bp + 32); \
        const short8 b2 = *(const short8*)(bp + 64); \
        ACC = __builtin_amdgcn_mfma_f32_16x16x32_bf16(ofr0, b0, ACC, 0, 0, 0); \
        ACC = __builtin_amdgcn_mfma_f32_16x16x32_bf16(ofr1, b1, ACC, 0, 0, 0); \
        ACC = __builtin_amdgcn_mfma_f32_16x16x32_bf16(ofr2, b2, ACC, 0, 0, 0); }
        PRJ_TILE(0, pa0) PRJ_TILE(1, pa1) PRJ_TILE(2, pa2)
#undef PRJ_TILE
        const int gi = (wi * 4 + tr + 2) & 15;
        const int gx = (wx * 4 + lg + 2) & 63;
#define PRJ_ST(CT, ACC) { \
        const int col = chf*48 + (CT)*16 + lr; \
        const float pb = projb[col]; \
        _Pragma("unroll") \
        for (int r = 0; r < 4; ++r) { \
            const int gt = (wt * 4 + r + 2) & 63; \
            const int l = (gi << 12) + (gx << 6) + gt; \
            const size_t base = ((size_t)bb * 65536 + l) * 96 + col; \
            y[base] = x[base] + ACC[r] + pb; \
        } }
        PRJ_ST(0, pa0) PRJ_ST(1, pa1) PRJ_ST(2, pa2)
#undef PRJ_ST
    }
}

// ---------------- Kernel B: LN2 + MLP (gelu) via MFMA + residual ----------------
__global__ __launch_bounds__(512, 2)
void swin_mlp_kernel(const float* __restrict__ y,
                     const float* __restrict__ n2g, const float* __restrict__ n2b,
                     const float* __restrict__ w1p, const float* __restrict__ b1p,
                     const float* __restrict__ w2p, const float* __restrict__ b2p,
                     float* __restrict__ out)
{
    __shared__ __align__(16) ushort h2A[128 * 104];  // LN2 out bf16 [tok][k]
    __shared__ __align__(16) ushort t1A[128 * 104];  // gelu tile bf16 [tok][hcol]
    __shared__ __align__(16) ushort w1T[96 * 104];   // w1 tile^T [col][k]
    __shared__ __align__(16) ushort w2T[96 * 104];   // w2 chunk^T [col][k]

    const int tid = threadIdx.x;
    const size_t tok0 = (size_t)blockIdx.x * 128;

    // ---- phase 1: LayerNorm2 -> h2A bf16 ----
    {
        const int tk = tid >> 2, q4 = tid & 3;
        const float* src = y + (tok0 + tk) * 96 + q4 * 24;
        float v[24];
        #pragma unroll
        for (int i = 0; i < 6; ++i) {
            const float4 t = *(const float4*)(src + i * 4);
            v[i*4+0]=t.x; v[i*4+1]=t.y; v[i*4+2]=t.z; v[i*4+3]=t.w;
        }
        float s = 0.f, ss = 0.f;
        #pragma unroll
        for (int i = 0; i < 24; ++i) { s += v[i]; ss += v[i]*v[i]; }
        s += __shfl_xor(s, 1); s += __shfl_xor(s, 2);
        ss += __shfl_xor(ss, 1); ss += __shfl_xor(ss, 2);
        const float mean = s * (1.f/96.f);
        const float rstd = rsqrtf(ss * (1.f/96.f) - mean*mean + 1e-5f);
        float nv[24];
        #pragma unroll
        for (int i = 0; i < 24; ++i) {
            const int ch = q4 * 24 + i;
            nv[i] = (v[i]-mean)*rstd*n2g[ch] + n2b[ch];
        }
        #pragma unroll
        for (int j = 0; j < 12; ++j)
            *(uint*)&h2A[tk * 104 + q4 * 24 + 2 * j] = pk2(nv[2*j], nv[2*j+1]);
    }
    __syncthreads();

    const int wv = tid >> 6, lane = tid & 63;
    const int lr = lane & 15, lg = lane >> 4;

    const short8 hfr0 = *(const short8*)&h2A[(wv*16 + lr) * 104 +  0 + lg * 8];
    const short8 hfr1 = *(const short8*)&h2A[(wv*16 + lr) * 104 + 32 + lg * 8];
    const short8 hfr2 = *(const short8*)&h2A[(wv*16 + lr) * 104 + 64 + lg * 8];

    floatx4 ao0 = {0.f,0.f,0.f,0.f}, ao1 = {0.f,0.f,0.f,0.f}, ao2 = {0.f,0.f,0.f,0.f},
            ao3 = {0.f,0.f,0.f,0.f}, ao4 = {0.f,0.f,0.f,0.f}, ao5 = {0.f,0.f,0.f,0.f};

    for (int jt = 0; jt < 4; ++jt) {
        if (jt) __syncthreads();
        // stage w1[:, jt*96..+96]^T and w2[jt*96..+96, :]^T (bf16, k-pairs packed)
        #pragma unroll
        for (int it = 0; it < 5; ++it) {
            const int idx = tid + it * 512;
            if (idx < 1152) {
                const int rp = idx / 24, c4 = idx - rp * 24;
                const float* s0 = w1p + (2 * rp) * 384 + jt * 96 + c4 * 4;
                const float4 r0 = *(const float4*)s0;
                const float4 r1 = *(const float4*)(s0 + 384);
                const int base = (c4 * 4) * 104 + 2 * rp;
                *(uint*)&w1T[base      ] = pk2(r0.x, r1.x);
                *(uint*)&w1T[base + 104] = pk2(r0.y, r1.y);
                *(uint*)&w1T[base + 208] = pk2(r0.z, r1.z);
                *(uint*)&w1T[base + 312] = pk2(r0.w, r1.w);
            } else if (idx < 2304) {
                const int k2 = idx - 1152;
                const int rp = k2 / 24, c4 = k2 - rp * 24;
                const float* s0 = w2p + (jt * 96 + 2 * rp) * 96 + c4 * 4;
                const float4 r0 = *(const float4*)s0;
                const float4 r1 = *(const float4*)(s0 + 96);
                const int base = (c4 * 4) * 104 + 2 * rp;
                *(uint*)&w2T[base      ] = pk2(r0.x, r1.x);
                *(uint*)&w2T[base + 104] = pk2(r0.y, r1.y);
                *(uint*)&w2T[base + 208] = pk2(r0.z, r1.z);
                *(uint*)&w2T[base + 312] = pk2(r0.w, r1.w);
            }
        }
        __syncthreads();
        // GEMM1 + bias + gelu -> t1A (own token tile rows; wave-local)
#define MLP1_TILE(CT) { \
        const ushort* bp = &w1T[((CT)*16 + lr) * 104 + lg * 8]; \
        const short8 b0 = *(const short8*)(bp); \
        const short8 b1 = *(const short8*)(bp + 32); \
        const short8 b2 = *(const short8*)(bp + 64); \
        floatx4 a1 = {0.f,0.f,0.f,0.f}; \
        a1 = __builtin_amdgcn_mfma_f32_16x16x32_bf16(hfr0, b0, a1, 0, 0, 0); \
        a1 = __builtin_amdgcn_mfma_f32_16x16x32_bf16(hfr1, b1, a1, 0, 0, 0); \
        a1 = __builtin_amdgcn_mfma_f32_16x16x32_bf16(hfr2, b2, a1, 0, 0, 0); \
        const float bv = b1p[jt * 96 + (CT)*16 + lr]; \
        _Pragma("unroll") \
        for (int r = 0; r < 4; ++r) { \
            float t = a1[r] + bv; \
            t = 0.5f * t * (1.f + erff(t * 0.70710678118654752f)); \
            t1A[(wv*16 + lg*4 + r) * 104 + (CT)*16 + lr] = f2bf(t); \
        } }
        MLP1_TILE(0) MLP1_TILE(1) MLP1_TILE(2) MLP1_TILE(3) MLP1_TILE(4) MLP1_TILE(5)
#undef MLP1_TILE
        // GEMM2: A from own t1A rows (same-wave LDS ordering), accumulate out
        const short8 tf0 = *(const short8*)&t1A[(wv*16 + lr) * 104 +  0 + lg * 8];
        const short8 tf1 = *(const short8*)&t1A[(wv*16 + lr) * 104 + 32 + lg * 8];
        const short8 tf2 = *(const short8*)&t1A[(wv*16 + lr) * 104 + 64 + lg * 8];
#define MLP2_TILE(CO, AO) { \
        const ushort* bp = &w2T[((CO)*16 + lr) * 104 + lg * 8]; \
        const short8 b0 = *(const short8*)(bp); \
        const short8 b1 = *(const short8*)(bp + 32); \
        const short8 b2 = *(const short8*)(bp + 64); \
        AO = __builtin_amdgcn_mfma_f32_16x16x32_bf16(tf0, b0, AO, 0, 0, 0); \
        AO = __builtin_amdgcn_mfma_f32_16x16x32_bf16(tf1, b1, AO, 0, 0, 0); \
        AO = __builtin_amdgcn_mfma_f32_16x16x32_bf16(tf2, b2, AO, 0, 0, 0); }
        MLP2_TILE(0, ao0) MLP2_TILE(1, ao1) MLP2_TILE(2, ao2)
        MLP2_TILE(3, ao3) MLP2_TILE(4, ao4) MLP2_TILE(5, ao5)
#undef MLP2_TILE
    }

    // ---- epilogue: out = y + mlp + b2 ----
#define MLP_OUT(CO, AO) { \
    const int col = (CO)*16 + lr; \
    const float bb2 = b2p[col]; \
    _Pragma("unroll") \
    for (int r = 0; r < 4; ++r) { \
        const size_t base = (tok0 + wv*16 + lg*4 + r) * 96 + col; \
        out[base] = y[base] + AO[r] + bb2; \
    } }
    MLP_OUT(0, ao0) MLP_OUT(1, ao1) MLP_OUT(2, ao2)
    MLP_OUT(3, ao3) MLP_OUT(4, ao4) MLP_OUT(5, ao5)
#undef MLP_OUT
}

extern "C" void kernel_launch(void* const* d_in, const int* in_sizes, int n_in,
                              void* d_out, int out_size, void* d_ws, size_t ws_size,
                              hipStream_t stream) {
    (void)in_sizes; (void)n_in; (void)d_ws; (void)ws_size; (void)out_size;
    const float* x     = (const float*)d_in[0];
    const float* n1g   = (const float*)d_in[1];
    const float* n1b   = (const float*)d_in[2];
    const float* qkvw  = (const float*)d_in[3];
    const float* qkvb  = (const float*)d_in[4];
    const float* projw = (const float*)d_in[5];
    const float* projb = (const float*)d_in[6];
    const float* btab  = (const float*)d_in[7];
    const float* n2g   = (const float*)d_in[8];
    const float* n2b   = (const float*)d_in[9];
    const float* w1    = (const float*)d_in[10];
    const float* b1    = (const float*)d_in[11];
    const float* w2    = (const float*)d_in[12];
    const float* b2    = (const float*)d_in[13];
    float* out = (float*)d_out;

    swin_attn_kernel<<<2048, 512, 0, stream>>>(x, n1g, n1b, qkvw, qkvb,
                                               projw, projb, btab, out);
    swin_mlp_kernel<<<1024, 512, 0, stream>>>(out, n2g, n2b, w1, b1, w2, b2, out);
}

// Round 8
// 276.795 us; speedup vs baseline: 3.5367x; 1.4947x over previous
//
#include <hip/hip_runtime.h>
#include <math.h>

// SwinTransformerBlock3D: B=2, grid(16,64,64) -> L=65536, C=96, H=6, hd=16,
// win 4^3 -> N=64 tokens/window, shift (2,2,2), 2048 windows, MLP hidden 384.
// All I/O float32.
// R8: (1) attention QK^T/PV -> mfma_16x16x32_bf16 with lane-local softmax
//     (S^T trick: C col = q, rows = k -> per-lane 16 k-values, no shuffles).
//     Slot-consistency: both operands of every mfma are filled with the SAME
//     (lanegroup,slot)->k map, so only the m89-verified C layout matters.
//     (2) weights pre-converted once/call to bf16-transposed in d_ws (240 KB);
//     kernels read weight fragments directly from global (L1-shared).
//     (3) kB: swapped GEMM1 (packed uint t1A writes), wave-local t1A (1 barrier),
//     53 KB LDS -> 2 blocks/CU. kA LDS 78.6 KB -> 2 blocks/CU.

typedef __attribute__((ext_vector_type(8))) short short8;
typedef __attribute__((ext_vector_type(4))) float floatx4;
typedef unsigned short ushort;
typedef unsigned int uint;

__device__ __forceinline__ ushort f2bf(float f) {
    union { float f; uint u; } v; v.f = f;
    uint r = v.u + 0x7FFFu + ((v.u >> 16) & 1u);   // RNE
    return (ushort)(r >> 16);
}
__device__ __forceinline__ uint pk2(float a, float b) {
    return (uint)f2bf(a) | ((uint)f2bf(b) << 16);
}
union U8 { uint u[4]; short8 s8; };

// ws layout (ushort, row stride 104, k index 0..95 within row):
// rows 0..287   : qkvwT  row = jt*96 + col   (col of qkv tile jt)
// rows 288..383 : projwT row = col
// rows 384..767 : w1T    row = jt*96 + hcol
// rows 768..1151: w2T    row = jt*96 + outcol (k = hidden within chunk jt)
#define WS_QKV  0
#define WS_PROJ (288 * 104)
#define WS_W1   (384 * 104)
#define WS_W2   (768 * 104)

// ---------------- weight pre-conversion (runs every call; ws re-poisoned) ----
__global__ __launch_bounds__(512, 8)
void convert_w(const float* __restrict__ qkvw, const float* __restrict__ projw,
               const float* __restrict__ w1, const float* __restrict__ w2,
               ushort* __restrict__ ws)
{
    const int idx = blockIdx.x * 512 + threadIdx.x;   // 48 k-pairs x 1152 rows
    const int kk = idx / 1152;
    const int r  = idx - kk * 1152;
    const int k0 = 2 * kk, k1 = k0 + 1;
    float a, b;
    if (r < 288)      { a = qkvw[k0 * 288 + r];              b = qkvw[k1 * 288 + r]; }
    else if (r < 384) { const int c = r - 288;  a = projw[k0 * 96 + c];  b = projw[k1 * 96 + c]; }
    else if (r < 768) { const int c = r - 384;  a = w1[k0 * 384 + c];    b = w1[k1 * 384 + c]; }
    else {
        const int c0 = r - 768;
        const int jt = c0 / 96, c = c0 - jt * 96;
        a = w2[(jt * 96 + k0) * 96 + c];
        b = w2[(jt * 96 + k1) * 96 + c];
    }
    *(uint*)&ws[r * 104 + k0] = pk2(a, b);
}

// ---------------- Kernel A: LN1 + window attention + proj + residual --------
__global__ __launch_bounds__(512, 4)
void swin_attn_kernel(const float* __restrict__ x,
                      const float* __restrict__ n1g, const float* __restrict__ n1b,
                      const ushort* __restrict__ ws,
                      const float* __restrict__ qkvb,
                      const float* __restrict__ projb,
                      const float* __restrict__ btab,
                      float* __restrict__ y)
{
    __shared__ __align__(16) ushort hA[64 * 104];    // LN1 out bf16 [tok][k]
    __shared__ __align__(16) ushort qS[6 * 64 * 20]; // q bf16 [head][tok][d], *0.25
    __shared__ __align__(16) ushort kS[6 * 64 * 20]; // k bf16 [head][tok][d]
    __shared__ __align__(16) ushort vT[6 * 16 * 68]; // v^T bf16 [head][d][tok]
    __shared__ __align__(16) ushort oA[64 * 104];    // attn out bf16 [tok][ch]
    __shared__ __align__(16) float  bias_s[343 * 6]; // btab copy

    const int tid = threadIdx.x;
    const int wid = blockIdx.x;
    const int bb = wid >> 10;
    const int wi = (wid >> 8) & 3;
    const int wx = (wid >> 4) & 15;
    const int wt = wid & 15;

    // ---- phase 1: gather (roll -2) + LayerNorm1 -> hA; stage bias table ----
    for (int i = tid; i < 343 * 6; i += 512) bias_s[i] = btab[i];
    {
        const int n = tid >> 3, p = tid & 7;
        const int a = n >> 4, c = (n >> 2) & 3, e = n & 3;
        const int gi = (wi * 4 + a + 2) & 15;
        const int gx = (wx * 4 + c + 2) & 63;
        const int gt = (wt * 4 + e + 2) & 63;
        const int l = (gi << 12) + (gx << 6) + gt;
        const float* src = x + ((size_t)bb * 65536 + l) * 96 + p * 12;
        float v[12];
        #pragma unroll
        for (int i = 0; i < 3; ++i) {
            const float4 t = *(const float4*)(src + i * 4);
            v[i*4+0] = t.x; v[i*4+1] = t.y; v[i*4+2] = t.z; v[i*4+3] = t.w;
        }
        float s = 0.f, ss = 0.f;
        #pragma unroll
        for (int i = 0; i < 12; ++i) { s += v[i]; ss += v[i] * v[i]; }
        s  += __shfl_xor(s, 1);  s  += __shfl_xor(s, 2);  s  += __shfl_xor(s, 4);
        ss += __shfl_xor(ss, 1); ss += __shfl_xor(ss, 2); ss += __shfl_xor(ss, 4);
        const float mean = s * (1.f / 96.f);
        const float rstd = rsqrtf(ss * (1.f / 96.f) - mean * mean + 1e-5f);
        float nv[12];
        #pragma unroll
        for (int i = 0; i < 12; ++i) {
            const int ch = p * 12 + i;
            nv[i] = (v[i] - mean) * rstd * n1g[ch] + n1b[ch];
        }
        #pragma unroll
        for (int j = 0; j < 6; ++j)
            *(uint*)&hA[n * 104 + p * 12 + 2 * j] = pk2(nv[2*j], nv[2*j+1]);
    }
    __syncthreads();

    const int wv = tid >> 6, lane = tid & 63;
    const int lr = lane & 15, lg = lane >> 4;
    const int tr = wv >> 1;        // token tile (0..3)
    const int chf = wv & 1;        // col half (48 cols)

    // B-fragments from hA (N = tokens), reused across jt
    const short8 hfr0 = *(const short8*)&hA[(tr*16 + lr) * 104 +  0 + lg * 8];
    const short8 hfr1 = *(const short8*)&hA[(tr*16 + lr) * 104 + 32 + lg * 8];
    const short8 hfr2 = *(const short8*)&hA[(tr*16 + lr) * 104 + 64 + lg * 8];

    // ---- phase 2: QKV via swapped MFMA (C: col=token, row=qkv-col) ----
    #pragma unroll
    for (int jt = 0; jt < 3; ++jt) {
#define QKV_CT(CT) { \
        const ushort* wp = ws + WS_QKV + ((jt*96 + chf*48 + (CT)*16 + lr) * 104 + lg * 8); \
        floatx4 acc = {0.f,0.f,0.f,0.f}; \
        acc = __builtin_amdgcn_mfma_f32_16x16x32_bf16(*(const short8*)(wp     ), hfr0, acc, 0,0,0); \
        acc = __builtin_amdgcn_mfma_f32_16x16x32_bf16(*(const short8*)(wp + 32), hfr1, acc, 0,0,0); \
        acc = __builtin_amdgcn_mfma_f32_16x16x32_bf16(*(const short8*)(wp + 64), hfr2, acc, 0,0,0); \
        const int colb = chf*48 + (CT)*16 + lg*4; \
        const int hh = colb >> 4, db = colb & 15; \
        const int tok = tr*16 + lr; \
        const float4 b4 = *(const float4*)&qkvb[jt*96 + colb]; \
        const float v0 = acc[0] + b4.x, v1 = acc[1] + b4.y; \
        const float v2 = acc[2] + b4.z, v3 = acc[3] + b4.w; \
        if (jt == 0) { \
            *(uint*)&qS[(hh*64 + tok)*20 + db    ] = pk2(v0*0.25f, v1*0.25f); \
            *(uint*)&qS[(hh*64 + tok)*20 + db + 2] = pk2(v2*0.25f, v3*0.25f); \
        } else if (jt == 1) { \
            *(uint*)&kS[(hh*64 + tok)*20 + db    ] = pk2(v0, v1); \
            *(uint*)&kS[(hh*64 + tok)*20 + db + 2] = pk2(v2, v3); \
        } else { \
            vT[(hh*16 + db + 0)*68 + tok] = f2bf(v0); \
            vT[(hh*16 + db + 1)*68 + tok] = f2bf(v1); \
            vT[(hh*16 + db + 2)*68 + tok] = f2bf(v2); \
            vT[(hh*16 + db + 3)*68 + tok] = f2bf(v3); \
        } }
        QKV_CT(0) QKV_CT(1) QKV_CT(2)
#undef QKV_CT
    }
    __syncthreads();

    // ---- phase 3: attention via MFMA, lane-local softmax ----
    // unit = (head, qt); 24 units over 8 waves (3 each). Per lane: q = qt*16+lr.
    {
        const int c1 = lr >> 2, e1 = lr & 3;   // query coord parts
        #pragma unroll
        for (int iu = 0; iu < 3; ++iu) {
            const int unit = wv * 3 + iu;
            const int head = unit >> 2, qt = unit & 3;
            // B = Q fragment (slots 0..3 = d lg*4+i, 4..7 = zero)
            U8 qf;
            { const uint2 qb = *(const uint2*)&qS[(head*64 + qt*16 + lr)*20 + lg*4];
              qf.u[0] = qb.x; qf.u[1] = qb.y; qf.u[2] = 0u; qf.u[3] = 0u; }
            float sc[16];
            #pragma unroll
            for (int kt = 0; kt < 4; ++kt) {
                U8 kf;
                { const uint2 kb = *(const uint2*)&kS[(head*64 + kt*16 + lr)*20 + lg*4];
                  kf.u[0] = kb.x; kf.u[1] = kb.y; kf.u[2] = 0u; kf.u[3] = 0u; }
                floatx4 z = {0.f,0.f,0.f,0.f};
                z = __builtin_amdgcn_mfma_f32_16x16x32_bf16(kf.s8, qf.s8, z, 0,0,0);
                #pragma unroll
                for (int r = 0; r < 4; ++r) {
                    const int ridx = ((qt - kt + 3)*7 + (c1 - lg + 3))*7 + (e1 - r + 3);
                    sc[kt*4+r] = z[r] + bias_s[ridx*6 + head];
                }
            }
            // per-lane softmax over the 16 k-values
            float mx = sc[0];
            #pragma unroll
            for (int j = 1; j < 16; ++j) mx = fmaxf(mx, sc[j]);
            float pn[16]; float sum = 0.f;
            #pragma unroll
            for (int j = 0; j < 16; ++j) { pn[j] = __expf(sc[j] - mx); sum += pn[j]; }
            const float inv = 1.f / sum;
            #pragma unroll
            for (int j = 0; j < 16; ++j) pn[j] *= inv;
            // P fragments: chunk c slots i -> k = (2c + (i>>2))*16? No: by-construction
            // map k(lg,i) = c*32 + (i>>2)*16 + lg*4 + (i&3); V^T read uses same map.
            U8 pf0, pf1;
            pf0.u[0] = pk2(pn[0],  pn[1]);  pf0.u[1] = pk2(pn[2],  pn[3]);
            pf0.u[2] = pk2(pn[4],  pn[5]);  pf0.u[3] = pk2(pn[6],  pn[7]);
            pf1.u[0] = pk2(pn[8],  pn[9]);  pf1.u[1] = pk2(pn[10], pn[11]);
            pf1.u[2] = pk2(pn[12], pn[13]); pf1.u[3] = pk2(pn[14], pn[15]);
            U8 vf0, vf1;
            { const uint2 va = *(const uint2*)&vT[(head*16 + lr)*68 +  0 + lg*4];
              const uint2 vb = *(const uint2*)&vT[(head*16 + lr)*68 + 16 + lg*4];
              vf0.u[0] = va.x; vf0.u[1] = va.y; vf0.u[2] = vb.x; vf0.u[3] = vb.y; }
            { const uint2 va = *(const uint2*)&vT[(head*16 + lr)*68 + 32 + lg*4];
              const uint2 vb = *(const uint2*)&vT[(head*16 + lr)*68 + 48 + lg*4];
              vf1.u[0] = va.x; vf1.u[1] = va.y; vf1.u[2] = vb.x; vf1.u[3] = vb.y; }
            floatx4 o = {0.f,0.f,0.f,0.f};
            o = __builtin_amdgcn_mfma_f32_16x16x32_bf16(vf0.s8, pf0.s8, o, 0,0,0);
            o = __builtin_amdgcn_mfma_f32_16x16x32_bf16(vf1.s8, pf1.s8, o, 0,0,0);
            // C: col = q (lr), row = d (lg*4+r) -> oA[q][head*16 + d]
            *(uint*)&oA[(qt*16 + lr)*104 + head*16 + lg*4    ] = pk2(o[0], o[1]);
            *(uint*)&oA[(qt*16 + lr)*104 + head*16 + lg*4 + 2] = pk2(o[2], o[3]);
        }
    }
    __syncthreads();

    // ---- phase 4: proj via swapped MFMA + residual -> y (float4 stores) ----
    {
        const short8 ofr0 = *(const short8*)&oA[(tr*16 + lr) * 104 +  0 + lg * 8];
        const short8 ofr1 = *(const short8*)&oA[(tr*16 + lr) * 104 + 32 + lg * 8];
        const short8 ofr2 = *(const short8*)&oA[(tr*16 + lr) * 104 + 64 + lg * 8];
        const int n = tr*16 + lr;
        const int gi = (wi * 4 + tr + 2) & 15;
        const int gx = (wx * 4 + (lr >> 2) + 2) & 63;
        const int gt = (wt * 4 + (lr & 3) + 2) & 63;
        const int l = (gi << 12) + (gx << 6) + gt;
        const size_t tbase = ((size_t)bb * 65536 + l) * 96;
        (void)n;
#define PRJ_CT(CT) { \
        const ushort* wp = ws + WS_PROJ + ((chf*48 + (CT)*16 + lr) * 104 + lg * 8); \
        floatx4 acc = {0.f,0.f,0.f,0.f}; \
        acc = __builtin_amdgcn_mfma_f32_16x16x32_bf16(*(const short8*)(wp     ), ofr0, acc, 0,0,0); \
        acc = __builtin_amdgcn_mfma_f32_16x16x32_bf16(*(const short8*)(wp + 32), ofr1, acc, 0,0,0); \
        acc = __builtin_amdgcn_mfma_f32_16x16x32_bf16(*(const short8*)(wp + 64), ofr2, acc, 0,0,0); \
        const int colb = chf*48 + (CT)*16 + lg*4; \
        const float4 pb4 = *(const float4*)&projb[colb]; \
        const float4 xv = *(const float4*)(x + tbase + colb); \
        float4 r; \
        r.x = xv.x + acc[0] + pb4.x; \
        r.y = xv.y + acc[1] + pb4.y; \
        r.z = xv.z + acc[2] + pb4.z; \
        r.w = xv.w + acc[3] + pb4.w; \
        *(float4*)(y + tbase + colb) = r; }
        PRJ_CT(0) PRJ_CT(1) PRJ_CT(2)
#undef PRJ_CT
    }
}

// ---------------- Kernel B: LN2 + MLP (gelu) via MFMA + residual ------------
__global__ __launch_bounds__(512, 4)
void swin_mlp_kernel(const float* __restrict__ y,
                     const float* __restrict__ n2g, const float* __restrict__ n2b,
                     const ushort* __restrict__ ws,
                     const float* __restrict__ b1p, const float* __restrict__ b2p,
                     float* __restrict__ out)
{
    __shared__ __align__(16) ushort h2A[128 * 104];  // LN2 out bf16 [tok][k]
    __shared__ __align__(16) ushort t1A[128 * 104];  // gelu bf16 [tok][hcol] (wave-local)

    const int tid = threadIdx.x;
    const size_t tok0 = (size_t)blockIdx.x * 128;

    // ---- phase 1: LayerNorm2 -> h2A bf16 ----
    {
        const int tk = tid >> 2, q4 = tid & 3;
        const float* src = y + (tok0 + tk) * 96 + q4 * 24;
        float v[24];
        #pragma unroll
        for (int i = 0; i < 6; ++i) {
            const float4 t = *(const float4*)(src + i * 4);
            v[i*4+0]=t.x; v[i*4+1]=t.y; v[i*4+2]=t.z; v[i*4+3]=t.w;
        }
        float s = 0.f, ss = 0.f;
        #pragma unroll
        for (int i = 0; i < 24; ++i) { s += v[i]; ss += v[i]*v[i]; }
        s += __shfl_xor(s, 1); s += __shfl_xor(s, 2);
        ss += __shfl_xor(ss, 1); ss += __shfl_xor(ss, 2);
        const float mean = s * (1.f/96.f);
        const float rstd = rsqrtf(ss * (1.f/96.f) - mean*mean + 1e-5f);
        float nv[24];
        #pragma unroll
        for (int i = 0; i < 24; ++i) {
            const int ch = q4 * 24 + i;
            nv[i] = (v[i]-mean)*rstd*n2g[ch] + n2b[ch];
        }
        #pragma unroll
        for (int j = 0; j < 12; ++j)
            *(uint*)&h2A[tk * 104 + q4 * 24 + 2 * j] = pk2(nv[2*j], nv[2*j+1]);
    }
    __syncthreads();   // only barrier in this kernel (t1A is wave-local)

    const int wv = tid >> 6, lane = tid & 63;
    const int lr = lane & 15, lg = lane >> 4;
    const int trow = (wv*16 + lr) * 104;

    const short8 hfr0 = *(const short8*)&h2A[trow +  0 + lg * 8];
    const short8 hfr1 = *(const short8*)&h2A[trow + 32 + lg * 8];
    const short8 hfr2 = *(const short8*)&h2A[trow + 64 + lg * 8];

    floatx4 a0 = {0.f,0.f,0.f,0.f}, a1 = {0.f,0.f,0.f,0.f}, a2 = {0.f,0.f,0.f,0.f},
            a3 = {0.f,0.f,0.f,0.f}, a4 = {0.f,0.f,0.f,0.f}, a5 = {0.f,0.f,0.f,0.f};

    #pragma unroll
    for (int jt = 0; jt < 4; ++jt) {
        // GEMM1 (swapped): C col=token(lr), row=hcol(lg*4+r) -> gelu -> t1A packed
#define M1_CT(CT) { \
        const ushort* wp = ws + WS_W1 + ((jt*96 + (CT)*16 + lr) * 104 + lg * 8); \
        floatx4 g = {0.f,0.f,0.f,0.f}; \
        g = __builtin_amdgcn_mfma_f32_16x16x32_bf16(*(const short8*)(wp     ), hfr0, g, 0,0,0); \
        g = __builtin_amdgcn_mfma_f32_16x16x32_bf16(*(const short8*)(wp + 32), hfr1, g, 0,0,0); \
        g = __builtin_amdgcn_mfma_f32_16x16x32_bf16(*(const short8*)(wp + 64), hfr2, g, 0,0,0); \
        const float4 bv = *(const float4*)&b1p[jt*96 + (CT)*16 + lg*4]; \
        float t0 = g[0] + bv.x, t1 = g[1] + bv.y, t2 = g[2] + bv.z, t3 = g[3] + bv.w; \
        t0 = 0.5f * t0 * (1.f + erff(t0 * 0.70710678118654752f)); \
        t1 = 0.5f * t1 * (1.f + erff(t1 * 0.70710678118654752f)); \
        t2 = 0.5f * t2 * (1.f + erff(t2 * 0.70710678118654752f)); \
        t3 = 0.5f * t3 * (1.f + erff(t3 * 0.70710678118654752f)); \
        *(uint*)&t1A[trow + (CT)*16 + lg*4    ] = pk2(t0, t1); \
        *(uint*)&t1A[trow + (CT)*16 + lg*4 + 2] = pk2(t2, t3); }
        M1_CT(0) M1_CT(1) M1_CT(2) M1_CT(3) M1_CT(4) M1_CT(5)
#undef M1_CT
        asm volatile("" ::: "memory");   // order t1A writes before reads (same wave)
        const short8 tf0 = *(const short8*)&t1A[trow +  0 + lg * 8];
        const short8 tf1 = *(const short8*)&t1A[trow + 32 + lg * 8];
        const short8 tf2 = *(const short8*)&t1A[trow + 64 + lg * 8];
#define M2_CO(CO, AO) { \
        const ushort* wp = ws + WS_W2 + ((jt*96 + (CO)*16 + lr) * 104 + lg * 8); \
        AO = __builtin_amdgcn_mfma_f32_16x16x32_bf16(*(const short8*)(wp     ), tf0, AO, 0,0,0); \
        AO = __builtin_amdgcn_mfma_f32_16x16x32_bf16(*(const short8*)(wp + 32), tf1, AO, 0,0,0); \
        AO = __builtin_amdgcn_mfma_f32_16x16x32_bf16(*(const short8*)(wp + 64), tf2, AO, 0,0,0); }
        M2_CO(0, a0) M2_CO(1, a1) M2_CO(2, a2) M2_CO(3, a3) M2_CO(4, a4) M2_CO(5, a5)
#undef M2_CO
        asm volatile("" ::: "memory");   // order t1A reads before next jt's writes
    }

    // ---- epilogue: out = y + mlp + b2 (float4, C col=token row=outcol) ----
    {
        const size_t base = (tok0 + wv*16 + lr) * 96;
#define M_OUT(CO, AO) { \
        const int colb = (CO)*16 + lg*4; \
        const float4 b2v = *(const float4*)&b2p[colb]; \
        const float4 yv = *(const float4*)(y + base + colb); \
        float4 r; \
        r.x = yv.x + AO[0] + b2v.x; \
        r.y = yv.y + AO[1] + b2v.y; \
        r.z = yv.z + AO[2] + b2v.z; \
        r.w = yv.w + AO[3] + b2v.w; \
        *(float4*)(out + base + colb) = r; }
        M_OUT(0, a0) M_OUT(1, a1) M_OUT(2, a2) M_OUT(3, a3) M_OUT(4, a4) M_OUT(5, a5)
#undef M_OUT
    }
}

extern "C" void kernel_launch(void* const* d_in, const int* in_sizes, int n_in,
                              void* d_out, int out_size, void* d_ws, size_t ws_size,
                              hipStream_t stream) {
    (void)in_sizes; (void)n_in; (void)ws_size; (void)out_size;
    const float* x     = (const float*)d_in[0];
    const float* n1g   = (const float*)d_in[1];
    const float* n1b   = (const float*)d_in[2];
    const float* qkvw  = (const float*)d_in[3];
    const float* qkvb  = (const float*)d_in[4];
    const float* projw = (const float*)d_in[5];
    const float* projb = (const float*)d_in[6];
    const float* btab  = (const float*)d_in[7];
    const float* n2g   = (const float*)d_in[8];
    const float* n2b   = (const float*)d_in[9];
    const float* w1    = (const float*)d_in[10];
    const float* b1    = (const float*)d_in[11];
    const float* w2    = (const float*)d_in[12];
    const float* b2    = (const float*)d_in[13];
    float* out = (float*)d_out;
    ushort* ws = (ushort*)d_ws;

    convert_w<<<108, 512, 0, stream>>>(qkvw, projw, w1, w2, ws);
    swin_attn_kernel<<<2048, 512, 0, stream>>>(x, n1g, n1b, ws, qkvb, projb, btab, out);
    swin_mlp_kernel<<<1024, 512, 0, stream>>>(out, n2g, n2b, ws, b1, b2, out);
}